// Round 17
// baseline (169.117 us; speedup 1.0000x reference)
//
#include <hip/hip_runtime.h>
#include <hip/hip_bf16.h>

#define NH 16
#define LQ 2048
#define SK 2048
#define QTILE 128
#define KVB 32
#define NSBLK (SK / KVB)           // 64
#define TILE_BYTES 8192            // K 4KB + V^T 4KB
#define MTILE_BYTES 8192           // mask tile: 64 lines x 128B
#define KV_BYTES ((size_t)4 * NH * NSBLK * TILE_BYTES)        // 32 MB
#define MASK_OFF KV_BYTES
#define MASK_BYTES ((size_t)16 * NSBLK * MTILE_BYTES)         // 8 MB
#define O1_OFF (MASK_OFF + MASK_BYTES)                        // 40 MB
#define O1_BYTES ((size_t)4 * NH * LQ * 64 * 4)               // 32 MB
#define Z0_OFF (O1_OFF + O1_BYTES)
#define Z_BYTES ((size_t)4 * NH * LQ * 4)                     // 512 KB
#define Z1_OFF (Z0_OFF + Z_BYTES)
#define WS_NEED_SPLIT (Z1_OFF + Z_BYTES)                      // 73 MB
#define WS_NEED (KV_BYTES + MASK_BYTES)                       // 40 MB
#define KSTR 72

typedef __bf16 bf16_t;
typedef bf16_t bf16x8 __attribute__((ext_vector_type(8)));
typedef bf16_t bf16x4 __attribute__((ext_vector_type(4)));
typedef bf16_t bf16x2 __attribute__((ext_vector_type(2)));
typedef float f32x16 __attribute__((ext_vector_type(16)));
typedef float f32x4 __attribute__((ext_vector_type(4)));
typedef unsigned int uint2v __attribute__((ext_vector_type(2)));
typedef unsigned int uint4v __attribute__((ext_vector_type(4)));

union U4B8 { uint4v u; bf16x8 v; };

__device__ __forceinline__ bf16x8 cvt8v(f32x4 a, f32x4 b) {
  bf16x8 r;
  r[0]=(bf16_t)a[0]; r[1]=(bf16_t)a[1]; r[2]=(bf16_t)a[2]; r[3]=(bf16_t)a[3];
  r[4]=(bf16_t)b[0]; r[5]=(bf16_t)b[1]; r[6]=(bf16_t)b[2]; r[7]=(bf16_t)b[3];
  return r;
}
__device__ __forceinline__ unsigned pk2(float lo, float hi) {
  bf16x2 t; t[0] = (bf16_t)lo; t[1] = (bf16_t)hi;
  return __builtin_bit_cast(unsigned, t);
}
__device__ __forceinline__ void gll16(const void* g, void* l) {
  __builtin_amdgcn_global_load_lds(
      (const __attribute__((address_space(1))) unsigned int*)g,
      (__attribute__((address_space(3))) unsigned int*)l, 16, 0, 0);
}

// ============================================================================
// repack_kv (KVB=32): per (bh, sblk) 8KB tile. [0,4K) K rows; [4K,8K) V^T
// lines {d|d+32} x 32kv. 16B chunks XOR-swizzled by (row&7)<<4.
// ============================================================================
__global__ __launch_bounds__(256) void repack_kv(const float* __restrict__ Kg,
                                                 const float* __restrict__ Vg,
                                                 unsigned char* __restrict__ ws)
{
  __shared__ __align__(16) unsigned short vlds[64 * 40];
  const int sblk = blockIdx.x, bh = blockIdx.y;
  const int b = bh >> 4, h = bh & 15;
  const int tid = threadIdx.x;
  const int row = tid >> 3;
  const int cq  = tid & 7;
  const int xr  = (row & 7) << 4;
  unsigned char* tile = ws + ((size_t)bh * NSBLK + sblk) * TILE_BYTES;

  {
    const float* kp = Kg + ((size_t)b * SK + sblk * KVB + row) * 1024 + h * 64 + cq * 8;
    f32x4 a = *(const f32x4*)kp;
    f32x4 b4 = *(const f32x4*)(kp + 4);
    *(bf16x8*)(tile + row * 128 + ((cq * 16) ^ xr)) = cvt8v(a, b4);
  }
  {
    const float* vp = Vg + ((size_t)b * SK + sblk * KVB + row) * 1024 + h * 64 + cq * 8;
    f32x4 a = *(const f32x4*)vp;
    f32x4 b4 = *(const f32x4*)(vp + 4);
    #pragma unroll
    for (int j = 0; j < 4; j++) {
      vlds[(cq * 8 + j) * 40 + row]     = __builtin_bit_cast(unsigned short, (bf16_t)a[j]);
      vlds[(cq * 8 + 4 + j) * 40 + row] = __builtin_bit_cast(unsigned short, (bf16_t)b4[j]);
    }
    __syncthreads();
    const int dp = row + 32 * (cq >> 2);
    const int kvc = cq & 3;
    bf16x8 r0 = *(const bf16x8*)&vlds[dp * 40 + kvc * 8];
    *(bf16x8*)(tile + 4096 + row * 128 + ((cq * 16) ^ xr)) = r0;
  }
}

// ============================================================================
// repack_mask (KVB=32): per (lt, t) 8KB tile, 64 lines x 128B.
// ============================================================================
__global__ __launch_bounds__(256) void repack_mask(const float* __restrict__ Mg,
                                                   unsigned char* __restrict__ mt)
{
  const int t = blockIdx.x, lt = blockIdx.y;
  const int tid = threadIdx.x;
  const int line = tid >> 2;
  const int xr   = (line & 7) << 4;
  unsigned char* tile = mt + ((size_t)lt * NSBLK + t) * MTILE_BYTES;
  #pragma unroll
  for (int cc = 0; cc < 2; cc++) {
    const int ch = (tid & 3) * 2 + cc;
    const int q  = lt * 128 + line + 64 * (ch >> 2);
    const int kv = t * KVB + (ch & 3) * 8;
    const float* src = Mg + (size_t)q * SK + kv;
    f32x4 a = *(const f32x4*)src;
    f32x4 b = *(const f32x4*)(src + 4);
    *(bf16x8*)(tile + line * 128 + ((ch * 16) ^ xr)) = cvt8v(a, b);
  }
}

// ============================================================================
// SPLIT main: grid 2048 (kv halved per block). Mask in REGISTERS (coalesced
// loads from repacked tiles); LDS 16KB -> ~6 blocks/CU. No division in
// epilogue: numerator + z written as partials; combine kernel finishes.
// ============================================================================
#define PFK(T_, KBUF)                                                            \
  {                                                                              \
    const unsigned char* sk_ = gsrc + (size_t)(T_) * TILE_BYTES;                 \
    unsigned char* lk_ = &(KBUF)[w * 1024];                                      \
    _Pragma("unroll")                                                            \
    for (int r_ = 0; r_ < 2; r_++) gll16(sk_ + r_ * 4096, lk_ + r_ * 4096);      \
  }

#define MLOADR(T_, MKP)                                                          \
  {                                                                              \
    const unsigned char* mp_ = gmaskL + (size_t)(T_) * MTILE_BYTES;              \
    _Pragma("unroll")                                                            \
    for (int u_ = 0; u_ < 4; u_++)                                               \
      MKP[u_] = *(const bf16x4*)(mp_ + mboff + ((mhalf + u_ * 16 + hi * 8) ^ mxr)); \
  }

#define SSTEP(KBUF, KNXT, MKCUR, MKNXT, T)                                       \
  {                                                                              \
    if ((T) + 1 < tend) { PFK((T) + 1, KNXT) MLOADR((T) + 1, MKNXT) }            \
    f32x16 s_;                                                                   \
    _Pragma("unroll")                                                            \
    for (int m_ = 0; m_ < 16; m_++) s_[m_] = 0.f;                                \
    __builtin_amdgcn_s_setprio(1);                                               \
    _Pragma("unroll")                                                            \
    for (int ec_ = 0; ec_ < 4; ec_++) {                                          \
      bf16x8 kf_ = *(const bf16x8*)((KBUF) + q32 * 128 + ((ec_ * 32 + hi * 16) ^ xr)); \
      s_ = __builtin_amdgcn_mfma_f32_32x32x16_bf16(kf_, qf[ec_], s_, 0, 0, 0);   \
    }                                                                            \
    __builtin_amdgcn_s_setprio(0);                                               \
    float ts_ = 0.f;                                                             \
    _Pragma("unroll")                                                            \
    for (int m_ = 0; m_ < 16; m_++) { s_[m_] = exp2f(s_[m_]); ts_ += s_[m_]; }   \
    zloc += ts_;                                                                 \
    _Pragma("unroll")                                                            \
    for (int m_ = 0; m_ < 16; m_++) s_[m_] *= (float)MKCUR[m_ >> 2][m_ & 3];     \
    bf16x8 pf_[2];                                                               \
    _Pragma("unroll")                                                            \
    for (int c_ = 0; c_ < 2; c_++) {                                             \
      unsigned a0_ = pk2(s_[8 * c_ + 0], s_[8 * c_ + 1]);                        \
      unsigned a1_ = pk2(s_[8 * c_ + 2], s_[8 * c_ + 3]);                        \
      unsigned b0_ = pk2(s_[8 * c_ + 4], s_[8 * c_ + 5]);                        \
      unsigned b1_ = pk2(s_[8 * c_ + 6], s_[8 * c_ + 7]);                        \
      uint2v r02_ = __builtin_amdgcn_permlane32_swap(a0_, b0_, false, false);    \
      uint2v r13_ = __builtin_amdgcn_permlane32_swap(a1_, b1_, false, false);    \
      U4B8 u_; u_.u = uint4v{r02_[0], r13_[0], r02_[1], r13_[1]};                \
      pf_[c_] = u_.v;                                                            \
    }                                                                            \
    __builtin_amdgcn_s_setprio(1);                                               \
    _Pragma("unroll")                                                            \
    for (int c_ = 0; c_ < 2; c_++) {                                             \
      bf16x8 vf0_ = *(const bf16x8*)((KBUF) + 4096 + q32 * 128 + ((c_ * 32 + hi * 16) ^ xr)); \
      acc0 = __builtin_amdgcn_mfma_f32_32x32x16_bf16(vf0_, pf_[c_], acc0, 0, 0, 0); \
      bf16x8 vf1_ = *(const bf16x8*)((KBUF) + 4096 + q32 * 128 + ((64 + c_ * 32 + hi * 16) ^ xr)); \
      acc1 = __builtin_amdgcn_mfma_f32_32x32x16_bf16(vf1_, pf_[c_], acc1, 0, 0, 0); \
    }                                                                            \
    __builtin_amdgcn_s_setprio(0);                                               \
    __syncthreads();                                                             \
  }

__global__ __launch_bounds__(256, 2)
void xattn_split(const float* __restrict__ Qg, unsigned char* __restrict__ WS,
                 float* __restrict__ Og)
{
  __shared__ __align__(16) unsigned char kb0[TILE_BYTES];
  __shared__ __align__(16) unsigned char kb1[TILE_BYTES];

  const int f   = blockIdx.x;               // 0..2047
  const int xcd = f & 7, ii = f >> 3;       // ii 0..255
  const int bh  = (xcd << 3) + (ii >> 5);   // 8 bh per XCD
  const int r5  = ii & 31;
  const int lt  = r5 >> 1;
  const int half = r5 & 1;
  const int b = bh >> 4, h = bh & 15;
  const int tid = threadIdx.x, w = tid >> 6, lane = tid & 63;
  const int q32 = lane & 31, hi = lane >> 5;
  const int qr0 = lt * QTILE + w * 32;
  const int xr  = (q32 & 7) << 4;
  const int mrow  = w * 32 + q32;
  const int mline = mrow & 63;
  const int mhalf = (mrow >> 6) << 6;
  const int mboff = mline * 128;
  const int mxr   = (mline & 7) << 4;
  const int tbase = half * (NSBLK / 2);
  const int tend  = tbase + NSBLK / 2;

  const float qs = 0.125f * 1.44269504088896340736f;
  bf16x8 qf[4];
  {
    const float* qp = Qg + ((size_t)b * LQ + qr0 + q32) * 1024 + h * 64 + hi * 8;
    #pragma unroll
    for (int ec = 0; ec < 4; ec++) {
      f32x4 x = *(const f32x4*)(qp + ec * 16);
      f32x4 y = *(const f32x4*)(qp + ec * 16 + 4);
      #pragma unroll
      for (int j = 0; j < 4; j++) { x[j] *= qs; y[j] *= qs; }
      qf[ec] = cvt8v(x, y);
    }
  }

  f32x16 acc0, acc1;
  #pragma unroll
  for (int m = 0; m < 16; m++) { acc0[m] = 0.f; acc1[m] = 0.f; }
  float zloc = 0.f;

  const unsigned char* gsrc   = WS + (size_t)bh * NSBLK * TILE_BYTES + tid * 16;
  const unsigned char* gmaskL = WS + MASK_OFF + (size_t)lt * NSBLK * MTILE_BYTES;

  bf16x4 mkA[4], mkB[4];

  PFK(tbase, kb0)
  MLOADR(tbase, mkA)
  __syncthreads();

  #pragma unroll 1
  for (int tp = 0; tp < NSBLK / 4; ++tp) {
    SSTEP(kb0, kb1, mkA, mkB, tbase + 2 * tp)
    SSTEP(kb1, kb0, mkB, mkA, tbase + 2 * tp + 1)
  }

  // ---- epilogue: write NUMERATOR partials + z (no division) ----
  {
    float zrun = zloc + __shfl_xor(zloc, 32);
    float* obase = (half == 0)
        ? (Og + ((size_t)bh * LQ + qr0 + q32) * 64 + hi * 4)
        : ((float*)(WS + O1_OFF) + ((size_t)bh * LQ + qr0 + q32) * 64 + hi * 4);
    #pragma unroll
    for (int mq = 0; mq < 4; mq++) {
      f32x4 o0, o1;
      #pragma unroll
      for (int r = 0; r < 4; r++) { o0[r] = acc0[4 * mq + r]; o1[r] = acc1[4 * mq + r]; }
      *(f32x4*)(obase + mq * 8) = o0;
      *(f32x4*)(obase + 32 + mq * 8) = o1;
    }
    if (hi == 0) {
      float* zb = (float*)(WS + (half == 0 ? Z0_OFF : Z1_OFF));
      zb[((size_t)bh << 11) + qr0 + q32] = zrun;
    }
  }
}

// ============================================================================
// combine: out = (out + O1) / (z0 + z1), elementwise f32x4.
// ============================================================================
__global__ __launch_bounds__(256) void combine(float* __restrict__ Og,
                                               const unsigned char* __restrict__ WS)
{
  const int i = blockIdx.x * 256 + threadIdx.x;   // per f32x4 chunk, 2M total
  const int row = i >> 4;                         // 16 chunks per 64-d row
  const float* z0 = (const float*)(WS + Z0_OFF);
  const float* z1 = (const float*)(WS + Z1_OFF);
  const f32x4* O1 = (const f32x4*)(WS + O1_OFF);
  float inv = 1.0f / (z0[row] + z1[row]);
  f32x4 a = ((f32x4*)Og)[i];
  f32x4 b = O1[i];
  #pragma unroll
  for (int j = 0; j < 4; j++) a[j] = (a[j] + b[j]) * inv;
  ((f32x4*)Og)[i] = a;
}

// ============================================================================
// tier-2 main (R16 verbatim): KVB=32, mask via LDS, grid 1024.
// ============================================================================
#define PF2(T_, KBUF, MBUF)                                                      \
  {                                                                              \
    const unsigned char* sk_ = gsrc + (size_t)(T_) * TILE_BYTES;                 \
    unsigned char* lk_ = &(KBUF)[w * 1024];                                      \
    _Pragma("unroll")                                                            \
    for (int r_ = 0; r_ < 2; r_++) gll16(sk_ + r_ * 4096, lk_ + r_ * 4096);      \
    const unsigned char* sm_ = gmask + (size_t)(T_) * MTILE_BYTES;               \
    unsigned char* lm_ = &(MBUF)[w * 1024];                                      \
    _Pragma("unroll")                                                            \
    for (int r_ = 0; r_ < 2; r_++) gll16(sm_ + r_ * 4096, lm_ + r_ * 4096);      \
  }

#define TILE_STEP(KBUF, MBUF, KNXT, MNXT, T)                                     \
  {                                                                              \
    if ((T) + 1 < NSBLK) { PF2((T) + 1, KNXT, MNXT) }                            \
    f32x16 s_;                                                                   \
    _Pragma("unroll")                                                            \
    for (int m_ = 0; m_ < 16; m_++) s_[m_] = 0.f;                                \
    __builtin_amdgcn_s_setprio(1);                                               \
    _Pragma("unroll")                                                            \
    for (int ec_ = 0; ec_ < 4; ec_++) {                                          \
      bf16x8 kf_ = *(const bf16x8*)((KBUF) + q32 * 128 + ((ec_ * 32 + hi * 16) ^ xr)); \
      s_ = __builtin_amdgcn_mfma_f32_32x32x16_bf16(kf_, qf[ec_], s_, 0, 0, 0);   \
    }                                                                            \
    __builtin_amdgcn_s_setprio(0);                                               \
    float ts_ = 0.f;                                                             \
    _Pragma("unroll")                                                            \
    for (int m_ = 0; m_ < 16; m_++) { s_[m_] = exp2f(s_[m_]); ts_ += s_[m_]; }   \
    zloc += ts_;                                                                 \
    bf16x4 mk_[4];                                                               \
    _Pragma("unroll")                                                            \
    for (int u_ = 0; u_ < 4; u_++)                                               \
      mk_[u_] = *(const bf16x4*)((MBUF) + mboff +                                \
                   ((mhalf + u_ * 16 + hi * 8) ^ mxr));                          \
    _Pragma("unroll")                                                            \
    for (int m_ = 0; m_ < 16; m_++) s_[m_] *= (float)mk_[m_ >> 2][m_ & 3];       \
    bf16x8 pf_[2];                                                               \
    _Pragma("unroll")                                                            \
    for (int c_ = 0; c_ < 2; c_++) {                                             \
      unsigned a0_ = pk2(s_[8 * c_ + 0], s_[8 * c_ + 1]);                        \
      unsigned a1_ = pk2(s_[8 * c_ + 2], s_[8 * c_ + 3]);                        \
      unsigned b0_ = pk2(s_[8 * c_ + 4], s_[8 * c_ + 5]);                        \
      unsigned b1_ = pk2(s_[8 * c_ + 6], s_[8 * c_ + 7]);                        \
      uint2v r02_ = __builtin_amdgcn_permlane32_swap(a0_, b0_, false, false);    \
      uint2v r13_ = __builtin_amdgcn_permlane32_swap(a1_, b1_, false, false);    \
      U4B8 u_; u_.u = uint4v{r02_[0], r13_[0], r02_[1], r13_[1]};                \
      pf_[c_] = u_.v;                                                            \
    }                                                                            \
    __builtin_amdgcn_s_setprio(1);                                               \
    _Pragma("unroll")                                                            \
    for (int c_ = 0; c_ < 2; c_++) {                                             \
      bf16x8 vf0_ = *(const bf16x8*)((KBUF) + 4096 + q32 * 128 + ((c_ * 32 + hi * 16) ^ xr)); \
      acc0 = __builtin_amdgcn_mfma_f32_32x32x16_bf16(vf0_, pf_[c_], acc0, 0, 0, 0); \
      bf16x8 vf1_ = *(const bf16x8*)((KBUF) + 4096 + q32 * 128 + ((64 + c_ * 32 + hi * 16) ^ xr)); \
      acc1 = __builtin_amdgcn_mfma_f32_32x32x16_bf16(vf1_, pf_[c_], acc1, 0, 0, 0); \
    }                                                                            \
    __builtin_amdgcn_s_setprio(0);                                               \
    __syncthreads();                                                             \
  }

__global__ __launch_bounds__(256, 2)
void xattn2(const float* __restrict__ Qg, const unsigned char* __restrict__ WS,
            float* __restrict__ Og)
{
  __shared__ __align__(16) unsigned char kb0[TILE_BYTES];
  __shared__ __align__(16) unsigned char kb1[TILE_BYTES];
  __shared__ __align__(16) unsigned char mb0[MTILE_BYTES];
  __shared__ __align__(16) unsigned char mb1[MTILE_BYTES];

  const int f   = blockIdx.x;
  const int xcd = f & 7, ii = f >> 3;
  const int bh  = (xcd << 3) + (ii >> 4);
  const int lt  = ii & 15;
  const int b = bh >> 4, h = bh & 15;
  const int tid = threadIdx.x, w = tid >> 6, lane = tid & 63;
  const int q32 = lane & 31, hi = lane >> 5;
  const int qr0 = lt * QTILE + w * 32;
  const int xr  = (q32 & 7) << 4;
  const int mrow  = w * 32 + q32;
  const int mline = mrow & 63;
  const int mhalf = (mrow >> 6) << 6;
  const int mboff = mline * 128;
  const int mxr   = (mline & 7) << 4;

  const float qs = 0.125f * 1.44269504088896340736f;
  bf16x8 qf[4];
  {
    const float* qp = Qg + ((size_t)b * LQ + qr0 + q32) * 1024 + h * 64 + hi * 8;
    #pragma unroll
    for (int ec = 0; ec < 4; ec++) {
      f32x4 x = *(const f32x4*)(qp + ec * 16);
      f32x4 y = *(const f32x4*)(qp + ec * 16 + 4);
      #pragma unroll
      for (int j = 0; j < 4; j++) { x[j] *= qs; y[j] *= qs; }
      qf[ec] = cvt8v(x, y);
    }
  }

  f32x16 acc0, acc1;
  #pragma unroll
  for (int m = 0; m < 16; m++) { acc0[m] = 0.f; acc1[m] = 0.f; }
  float zloc = 0.f;

  const unsigned char* gsrc  = WS + (size_t)bh * NSBLK * TILE_BYTES + tid * 16;
  const unsigned char* gmask = WS + MASK_OFF + (size_t)lt * NSBLK * MTILE_BYTES + tid * 16;

  PF2(0, kb0, mb0)
  __syncthreads();

  #pragma unroll 1
  for (int tp = 0; tp < NSBLK / 2; ++tp) {
    TILE_STEP(kb0, mb0, kb1, mb1, 2 * tp)
    TILE_STEP(kb1, mb1, kb0, mb0, 2 * tp + 1)
  }

  {
    float zrun = zloc + __shfl_xor(zloc, 32);
    float inv = 1.0f / zrun;
    float* op = Og + ((size_t)bh * LQ + qr0 + q32) * 64 + hi * 4;
    #pragma unroll
    for (int mq = 0; mq < 4; mq++) {
      f32x4 o0, o1;
      #pragma unroll
      for (int r = 0; r < 4; r++) { o0[r] = acc0[4 * mq + r] * inv; o1[r] = acc1[4 * mq + r] * inv; }
      *(f32x4*)(op + mq * 8) = o0;
      *(f32x4*)(op + 32 + mq * 8) = o1;
    }
  }
}

// ============================================================================
// tier-3 fallback (R4 kernel) for tiny ws
// ============================================================================
__global__ __launch_bounds__(256, 2)
void xattn_fwd(const float* __restrict__ Qg, const float* __restrict__ Kg,
               const float* __restrict__ Vg, const float* __restrict__ Mg,
               float* __restrict__ Og)
{
  __shared__ __align__(16) unsigned short Kt[64 * KSTR];
  __shared__ __align__(16) unsigned short Vt[64 * KSTR];
  const int f   = blockIdx.x + blockIdx.y * gridDim.x;
  const int xcd = f & 7;
  const int ii  = f >> 3;
  const int bh  = (xcd << 3) + (ii >> 4);
  const int lt  = ii & 15;
  const int b = bh >> 4, h = bh & 15;
  const int tid  = threadIdx.x;
  const int w    = tid >> 6;
  const int lane = tid & 63;
  const int q32  = lane & 31;
  const int hi   = lane >> 5;
  const int qr0  = lt * QTILE + w * 32;
  const float qs = 0.125f * 1.44269504088896340736f;
  bf16x8 qf[4];
  {
    const float* qp = Qg + ((size_t)b * LQ + qr0 + q32) * 1024 + h * 64 + hi * 8;
    #pragma unroll
    for (int ec = 0; ec < 4; ec++) {
      f32x4 x = *(const f32x4*)(qp + ec * 16);
      f32x4 y = *(const f32x4*)(qp + ec * 16 + 4);
      #pragma unroll
      for (int j = 0; j < 4; j++) { x[j] *= qs; y[j] *= qs; }
      qf[ec] = cvt8v(x, y);
    }
  }
  f32x16 acc0, acc1;
  #pragma unroll
  for (int m = 0; m < 16; m++) { acc0[m] = 0.f; acc1[m] = 0.f; }
  float mrun = -1e30f, zrun = 0.f;
  const int kr = tid >> 2;
  const int kc = (tid & 3) << 4;
  const int vd = tid & 63;
  const int vk0 = w << 4;
  const float* kbase = Kg + (size_t)b * SK * 1024 + h * 64;
  const float* vbase = Vg + (size_t)b * SK * 1024 + h * 64;
  const float* mbase = Mg + (size_t)(qr0 + q32) * SK + hi * 4;
  f32x4 ka, kb, kc4, kd;
  float vr[16];
  {
    const float* kp = kbase + (size_t)kr * 1024 + kc;
    ka = *(const f32x4*)kp;        kb = *(const f32x4*)(kp + 4);
    kc4 = *(const f32x4*)(kp + 8); kd = *(const f32x4*)(kp + 12);
    const float* vp = vbase + (size_t)vk0 * 1024 + vd;
    #pragma unroll
    for (int j = 0; j < 16; j++) vr[j] = vp[(size_t)j * 1024];
  }
  for (int s0 = 0; s0 < SK; s0 += 64) {
    bf16x8 kcv0 = cvt8v(ka, kb), kcv1 = cvt8v(kc4, kd);
    bf16x8 vcv0, vcv1;
    #pragma unroll
    for (int j = 0; j < 8; j++) { vcv0[j] = (bf16_t)vr[j]; vcv1[j] = (bf16_t)vr[8 + j]; }
    __syncthreads();
    *(bf16x8*)&Kt[kr * KSTR + kc] = kcv0;
    *(bf16x8*)&Kt[kr * KSTR + kc + 8] = kcv1;
    *(bf16x8*)&Vt[vd * KSTR + vk0] = vcv0;
    *(bf16x8*)&Vt[vd * KSTR + vk0 + 8] = vcv1;
    __syncthreads();
    f32x4 mk[8];
    {
      const float* mp = mbase + s0;
      #pragma unroll
      for (int kvt = 0; kvt < 2; kvt++)
        #pragma unroll
        for (int mq = 0; mq < 4; mq++)
          mk[kvt * 4 + mq] = *(const f32x4*)(mp + kvt * 32 + mq * 8);
    }
    if (s0 + 64 < SK) {
      const float* kp = kbase + (size_t)(s0 + 64 + kr) * 1024 + kc;
      ka = *(const f32x4*)kp;        kb = *(const f32x4*)(kp + 4);
      kc4 = *(const f32x4*)(kp + 8); kd = *(const f32x4*)(kp + 12);
      const float* vp = vbase + (size_t)(s0 + 64 + vk0) * 1024 + vd;
      #pragma unroll
      for (int j = 0; j < 16; j++) vr[j] = vp[(size_t)j * 1024];
    }
    f32x16 sT[2];
    #pragma unroll
    for (int m = 0; m < 16; m++) { sT[0][m] = 0.f; sT[1][m] = 0.f; }
    #pragma unroll
    for (int ec = 0; ec < 4; ec++) {
      bf16x8 kf0 = *(const bf16x8*)&Kt[q32 * KSTR + ec * 16 + hi * 8];
      sT[0] = __builtin_amdgcn_mfma_f32_32x32x16_bf16(kf0, qf[ec], sT[0], 0, 0, 0);
      bf16x8 kf1 = *(const bf16x8*)&Kt[(32 + q32) * KSTR + ec * 16 + hi * 8];
      sT[1] = __builtin_amdgcn_mfma_f32_32x32x16_bf16(kf1, qf[ec], sT[1], 0, 0, 0);
    }
    float rmax = sT[0][0];
    #pragma unroll
    for (int m = 1; m < 16; m++) rmax = fmaxf(rmax, sT[0][m]);
    #pragma unroll
    for (int m = 0; m < 16; m++) rmax = fmaxf(rmax, sT[1][m]);
    rmax = fmaxf(rmax, __shfl_xor(rmax, 32));
    if (!__all(rmax <= mrun + 6.0f)) {
      float nm = fmaxf(mrun, rmax);
      float corr = exp2f(mrun - nm);
      mrun = nm; zrun *= corr;
      #pragma unroll
      for (int m = 0; m < 16; m++) { acc0[m] *= corr; acc1[m] *= corr; }
    }
    float rs = 0.f;
    #pragma unroll
    for (int kvt = 0; kvt < 2; kvt++)
      #pragma unroll
      for (int m = 0; m < 16; m++) { sT[kvt][m] = exp2f(sT[kvt][m] - mrun); rs += sT[kvt][m]; }
    rs += __shfl_xor(rs, 32);
    zrun += rs;
    #pragma unroll
    for (int kvt = 0; kvt < 2; kvt++)
      #pragma unroll
      for (int m = 0; m < 16; m++) sT[kvt][m] *= mk[kvt * 4 + (m >> 2)][m & 3];
    bf16x8 pf[4];
    #pragma unroll
    for (int kvt = 0; kvt < 2; kvt++) {
      #pragma unroll
      for (int c = 0; c < 2; c++) {
        unsigned a0 = pk2(sT[kvt][8 * c + 0], sT[kvt][8 * c + 1]);
        unsigned a1 = pk2(sT[kvt][8 * c + 2], sT[kvt][8 * c + 3]);
        unsigned b0 = pk2(sT[kvt][8 * c + 4], sT[kvt][8 * c + 5]);
        unsigned b1 = pk2(sT[kvt][8 * c + 6], sT[kvt][8 * c + 7]);
        uint2v r02 = __builtin_amdgcn_permlane32_swap(a0, b0, false, false);
        uint2v r13 = __builtin_amdgcn_permlane32_swap(a1, b1, false, false);
        U4B8 u; u.u = uint4v{r02[0], r13[0], r02[1], r13[1]};
        pf[kvt * 2 + c] = u.v;
      }
    }
    #pragma unroll
    for (int c = 0; c < 4; c++) {
      bf16x8 vf0 = *(const bf16x8*)&Vt[q32 * KSTR + c * 16 + hi * 8];
      acc0 = __builtin_amdgcn_mfma_f32_32x32x16_bf16(vf0, pf[c], acc0, 0, 0, 0);
      bf16x8 vf1 = *(const bf16x8*)&Vt[(32 + q32) * KSTR + c * 16 + hi * 8];
      acc1 = __builtin_amdgcn_mfma_f32_32x32x16_bf16(vf1, pf[c], acc1, 0, 0, 0);
    }
  }
  {
    float inv = 1.0f / zrun;
    float* op = Og + ((size_t)bh * LQ + qr0 + q32) * 64 + hi * 4;
    #pragma unroll
    for (int mq = 0; mq < 4; mq++) {
      f32x4 o0, o1;
      #pragma unroll
      for (int r = 0; r < 4; r++) { o0[r] = acc0[4 * mq + r] * inv; o1[r] = acc1[4 * mq + r] * inv; }
      *(f32x4*)(op + mq * 8) = o0;
      *(f32x4*)(op + 32 + mq * 8) = o1;
    }
  }
}

extern "C" void kernel_launch(void* const* d_in, const int* in_sizes, int n_in,
                              void* d_out, int out_size, void* d_ws, size_t ws_size,
                              hipStream_t stream) {
  const float* Qg = (const float*)d_in[0];
  const float* Kg = (const float*)d_in[1];
  const float* Vg = (const float*)d_in[2];
  const float* Mg = (const float*)d_in[3];
  float* Og = (float*)d_out;
  if (ws_size >= WS_NEED_SPLIT) {
    unsigned char* ws = (unsigned char*)d_ws;
    repack_kv<<<dim3(NSBLK, 4 * NH), 256, 0, stream>>>(Kg, Vg, ws);
    repack_mask<<<dim3(NSBLK, 16), 256, 0, stream>>>(Mg, ws + MASK_OFF);
    xattn_split<<<2 * (LQ / QTILE) * 4 * NH, 256, 0, stream>>>(Qg, ws, Og);
    combine<<<(4 * NH * LQ * 64 / 4) / 256, 256, 0, stream>>>(Og, ws);
  } else if (ws_size >= WS_NEED) {
    unsigned char* ws = (unsigned char*)d_ws;
    repack_kv<<<dim3(NSBLK, 4 * NH), 256, 0, stream>>>(Kg, Vg, ws);
    repack_mask<<<dim3(NSBLK, 16), 256, 0, stream>>>(Mg, ws + MASK_OFF);
    xattn2<<<LQ / QTILE * 4 * NH, 256, 0, stream>>>(Qg, ws, Og);
  } else {
    xattn_fwd<<<dim3(LQ / QTILE, 4 * NH), 256, 0, stream>>>(Qg, Kg, Vg, Mg, Og);
  }
}

// Round 19
// 144.444 us; speedup vs baseline: 1.1708x; 1.1708x over previous
//
#include <hip/hip_runtime.h>
#include <hip/hip_bf16.h>

#define NH 16
#define LQ 2048
#define SK 2048
#define QTILE 128
#define KVB 32
#define NSBLK (SK / KVB)           // 64
#define TILE_BYTES 8192            // K 4KB (bf16) + V^T 4KB (fp16)
#define MTILE_BYTES 8192           // mask tile: 64 lines x 128B (fp16)
#define KV_BYTES ((size_t)4 * NH * NSBLK * TILE_BYTES)        // 32 MB
#define MASK_OFF KV_BYTES
#define MASK_BYTES ((size_t)16 * NSBLK * MTILE_BYTES)         // 8 MB
#define WS_NEED (KV_BYTES + MASK_BYTES)                       // 40 MB
#define KSTR 72

typedef __bf16 bf16_t;
typedef bf16_t bf16x8 __attribute__((ext_vector_type(8)));
typedef bf16_t bf16x4 __attribute__((ext_vector_type(4)));
typedef bf16_t bf16x2 __attribute__((ext_vector_type(2)));
typedef _Float16 f16_t;
typedef f16_t f16x8 __attribute__((ext_vector_type(8)));
typedef f16_t f16x4 __attribute__((ext_vector_type(4)));
typedef f16_t f16x2 __attribute__((ext_vector_type(2)));
typedef float f32x16 __attribute__((ext_vector_type(16)));
typedef float f32x4 __attribute__((ext_vector_type(4)));
typedef unsigned int uint2v __attribute__((ext_vector_type(2)));
typedef unsigned int uint4v __attribute__((ext_vector_type(4)));

union U4B8 { uint4v u; bf16x8 v; };
union U4H8 { uint4v u; f16x8 v; };

__device__ __forceinline__ bf16x8 cvt8v(f32x4 a, f32x4 b) {
  bf16x8 r;
  r[0]=(bf16_t)a[0]; r[1]=(bf16_t)a[1]; r[2]=(bf16_t)a[2]; r[3]=(bf16_t)a[3];
  r[4]=(bf16_t)b[0]; r[5]=(bf16_t)b[1]; r[6]=(bf16_t)b[2]; r[7]=(bf16_t)b[3];
  return r;
}
__device__ __forceinline__ f16x8 cvt8h(f32x4 a, f32x4 b) {
  f16x8 r;
  r[0]=(f16_t)a[0]; r[1]=(f16_t)a[1]; r[2]=(f16_t)a[2]; r[3]=(f16_t)a[3];
  r[4]=(f16_t)b[0]; r[5]=(f16_t)b[1]; r[6]=(f16_t)b[2]; r[7]=(f16_t)b[3];
  return r;
}
__device__ __forceinline__ unsigned pk2(float lo, float hi) {
  bf16x2 t; t[0] = (bf16_t)lo; t[1] = (bf16_t)hi;
  return __builtin_bit_cast(unsigned, t);
}
__device__ __forceinline__ f16x2 pkh(float lo, float hi) {
  return __builtin_bit_cast(f16x2, __builtin_amdgcn_cvt_pkrtz(lo, hi));
}
__device__ __forceinline__ void gll16(const void* g, void* l) {
  __builtin_amdgcn_global_load_lds(
      (const __attribute__((address_space(1))) unsigned int*)g,
      (__attribute__((address_space(3))) unsigned int*)l, 16, 0, 0);
}

// ============================================================================
// repack_kv (KVB=32): per (bh, sblk) 8KB tile.
//   [0,4K):  K rows kv=0..31 in bf16, 128B lines, 16B chunks XOR-swz (row&7)<<4
//   [4K,8K): V^T lines {d|d+32} x 32kv in FP16, same swizzle
// ============================================================================
__global__ __launch_bounds__(256) void repack_kv(const float* __restrict__ Kg,
                                                 const float* __restrict__ Vg,
                                                 unsigned char* __restrict__ ws)
{
  __shared__ __align__(16) unsigned short vlds[64 * 40];
  const int sblk = blockIdx.x, bh = blockIdx.y;
  const int b = bh >> 4, h = bh & 15;
  const int tid = threadIdx.x;
  const int row = tid >> 3;
  const int cq  = tid & 7;
  const int xr  = (row & 7) << 4;
  unsigned char* tile = ws + ((size_t)bh * NSBLK + sblk) * TILE_BYTES;

  {
    const float* kp = Kg + ((size_t)b * SK + sblk * KVB + row) * 1024 + h * 64 + cq * 8;
    f32x4 a = *(const f32x4*)kp;
    f32x4 b4 = *(const f32x4*)(kp + 4);
    *(bf16x8*)(tile + row * 128 + ((cq * 16) ^ xr)) = cvt8v(a, b4);
  }
  {
    const float* vp = Vg + ((size_t)b * SK + sblk * KVB + row) * 1024 + h * 64 + cq * 8;
    f32x4 a = *(const f32x4*)vp;
    f32x4 b4 = *(const f32x4*)(vp + 4);
    #pragma unroll
    for (int j = 0; j < 4; j++) {
      vlds[(cq * 8 + j) * 40 + row]     = __builtin_bit_cast(unsigned short, (f16_t)a[j]);
      vlds[(cq * 8 + 4 + j) * 40 + row] = __builtin_bit_cast(unsigned short, (f16_t)b4[j]);
    }
    __syncthreads();
    const int dp = row + 32 * (cq >> 2);
    const int kvc = cq & 3;
    f16x8 r0 = *(const f16x8*)&vlds[dp * 40 + kvc * 8];
    *(f16x8*)(tile + 4096 + row * 128 + ((cq * 16) ^ xr)) = r0;
  }
}

// ============================================================================
// repack_mask (KVB=32): per (lt, t) 8KB FP16 tile, 64 lines x 128B; line r =
// {mask[lt*128+r][t*32..] | mask[lt*128+r+64][...]}, chunk ch at (ch*16)^xr.
// ============================================================================
__global__ __launch_bounds__(256) void repack_mask(const float* __restrict__ Mg,
                                                   unsigned char* __restrict__ mt)
{
  const int t = blockIdx.x, lt = blockIdx.y;
  const int tid = threadIdx.x;
  const int line = tid >> 2;
  const int xr   = (line & 7) << 4;
  unsigned char* tile = mt + ((size_t)lt * NSBLK + t) * MTILE_BYTES;
  #pragma unroll
  for (int cc = 0; cc < 2; cc++) {
    const int ch = (tid & 3) * 2 + cc;
    const int q  = lt * 128 + line + 64 * (ch >> 2);
    const int kv = t * KVB + (ch & 3) * 8;
    const float* src = Mg + (size_t)q * SK + kv;
    f32x4 a = *(const f32x4*)src;
    f32x4 b = *(const f32x4*)(src + 4);
    *(f16x8*)(tile + line * 128 + ((ch * 16) ^ xr)) = cvt8h(a, b);
  }
}

// ============================================================================
// main (R16 structure): KVB=32, mask via LDS, grid 1024, 32KB LDS -> 4 blk/CU.
// R18 change: P packed via cvt_pkrtz, mask applied as packed v_pk_mul_f16,
// PV uses mfma_f32_32x32x16_f16 (V^T + mask tiles are fp16).
// ============================================================================
#define PF2(T_, KBUF, MBUF)                                                      \
  {                                                                              \
    const unsigned char* sk_ = gsrc + (size_t)(T_) * TILE_BYTES;                 \
    unsigned char* lk_ = &(KBUF)[w * 1024];                                      \
    _Pragma("unroll")                                                            \
    for (int r_ = 0; r_ < 2; r_++) gll16(sk_ + r_ * 4096, lk_ + r_ * 4096);      \
    const unsigned char* sm_ = gmask + (size_t)(T_) * MTILE_BYTES;               \
    unsigned char* lm_ = &(MBUF)[w * 1024];                                      \
    _Pragma("unroll")                                                            \
    for (int r_ = 0; r_ < 2; r_++) gll16(sm_ + r_ * 4096, lm_ + r_ * 4096);      \
  }

#define TILE_STEP(KBUF, MBUF, KNXT, MNXT, T)                                     \
  {                                                                              \
    if ((T) + 1 < NSBLK) { PF2((T) + 1, KNXT, MNXT) }                            \
    f32x16 s_;                                                                   \
    _Pragma("unroll")                                                            \
    for (int m_ = 0; m_ < 16; m_++) s_[m_] = 0.f;                                \
    __builtin_amdgcn_s_setprio(1);                                               \
    _Pragma("unroll")                                                            \
    for (int ec_ = 0; ec_ < 4; ec_++) {                                          \
      bf16x8 kf_ = *(const bf16x8*)((KBUF) + q32 * 128 + ((ec_ * 32 + hi * 16) ^ xr)); \
      s_ = __builtin_amdgcn_mfma_f32_32x32x16_bf16(kf_, qf[ec_], s_, 0, 0, 0);   \
    }                                                                            \
    __builtin_amdgcn_s_setprio(0);                                               \
    float ts_ = 0.f;                                                             \
    _Pragma("unroll")                                                            \
    for (int m_ = 0; m_ < 16; m_++) { s_[m_] = exp2f(s_[m_]); ts_ += s_[m_]; }   \
    zloc += ts_;                                                                 \
    /* mask (fp16): lane row = w*32+q32; chunk u covers kv = u*8+hi*4+{0..3} */  \
    f16x4 mk_[4];                                                                \
    _Pragma("unroll")                                                            \
    for (int u_ = 0; u_ < 4; u_++)                                               \
      mk_[u_] = *(const f16x4*)((MBUF) + mboff +                                 \
                   ((mhalf + u_ * 16 + hi * 8) ^ mxr));                          \
    /* P -> fp16 pairs, masked with v_pk_mul_f16, permlane32_swap to B-frags */  \
    f16x8 pf_[2];                                                                \
    _Pragma("unroll")                                                            \
    for (int c_ = 0; c_ < 2; c_++) {                                             \
      f16x2 a0_ = pkh(s_[8 * c_ + 0], s_[8 * c_ + 1]);                           \
      f16x2 a1_ = pkh(s_[8 * c_ + 2], s_[8 * c_ + 3]);                           \
      f16x2 b0_ = pkh(s_[8 * c_ + 4], s_[8 * c_ + 5]);                           \
      f16x2 b1_ = pkh(s_[8 * c_ + 6], s_[8 * c_ + 7]);                           \
      a0_ *= __builtin_shufflevector(mk_[2 * c_], mk_[2 * c_], 0, 1);            \
      a1_ *= __builtin_shufflevector(mk_[2 * c_], mk_[2 * c_], 2, 3);            \
      b0_ *= __builtin_shufflevector(mk_[2 * c_ + 1], mk_[2 * c_ + 1], 0, 1);    \
      b1_ *= __builtin_shufflevector(mk_[2 * c_ + 1], mk_[2 * c_ + 1], 2, 3);    \
      uint2v r02_ = __builtin_amdgcn_permlane32_swap(                            \
          __builtin_bit_cast(unsigned, a0_), __builtin_bit_cast(unsigned, b0_),  \
          false, false);                                                         \
      uint2v r13_ = __builtin_amdgcn_permlane32_swap(                            \
          __builtin_bit_cast(unsigned, a1_), __builtin_bit_cast(unsigned, b1_),  \
          false, false);                                                         \
      U4H8 u_; u_.u = uint4v{r02_[0], r13_[0], r02_[1], r13_[1]};                \
      pf_[c_] = u_.v;                                                            \
    }                                                                            \
    __builtin_amdgcn_s_setprio(1);                                               \
    _Pragma("unroll")                                                            \
    for (int c_ = 0; c_ < 2; c_++) {                                             \
      f16x8 vf0_ = *(const f16x8*)((KBUF) + 4096 + q32 * 128 + ((c_ * 32 + hi * 16) ^ xr)); \
      acc0 = __builtin_amdgcn_mfma_f32_32x32x16_f16(vf0_, pf_[c_], acc0, 0, 0, 0); \
      f16x8 vf1_ = *(const f16x8*)((KBUF) + 4096 + q32 * 128 + ((64 + c_ * 32 + hi * 16) ^ xr)); \
      acc1 = __builtin_amdgcn_mfma_f32_32x32x16_f16(vf1_, pf_[c_], acc1, 0, 0, 0); \
    }                                                                            \
    __builtin_amdgcn_s_setprio(0);                                               \
    __syncthreads();                                                             \
  }

__global__ __launch_bounds__(256, 2)
void xattn2(const float* __restrict__ Qg, const unsigned char* __restrict__ WS,
            float* __restrict__ Og)
{
  __shared__ __align__(16) unsigned char kb0[TILE_BYTES];
  __shared__ __align__(16) unsigned char kb1[TILE_BYTES];
  __shared__ __align__(16) unsigned char mb0[MTILE_BYTES];
  __shared__ __align__(16) unsigned char mb1[MTILE_BYTES];

  const int f   = blockIdx.x;
  const int xcd = f & 7, ii = f >> 3;
  const int bh  = (xcd << 3) + (ii >> 4);   // 8 bh per XCD
  const int lt  = ii & 15;
  const int b = bh >> 4, h = bh & 15;
  const int tid = threadIdx.x, w = tid >> 6, lane = tid & 63;
  const int q32 = lane & 31, hi = lane >> 5;
  const int qr0 = lt * QTILE + w * 32;
  const int xr  = (q32 & 7) << 4;
  const int mrow  = w * 32 + q32;
  const int mline = mrow & 63;
  const int mhalf = (mrow >> 6) << 6;
  const int mboff = mline * 128;
  const int mxr   = (mline & 7) << 4;

  // ---- Q B-frags (bf16), pre-scaled by (1/8)*log2(e) ----
  const float qs = 0.125f * 1.44269504088896340736f;
  bf16x8 qf[4];
  {
    const float* qp = Qg + ((size_t)b * LQ + qr0 + q32) * 1024 + h * 64 + hi * 8;
    #pragma unroll
    for (int ec = 0; ec < 4; ec++) {
      f32x4 x = *(const f32x4*)(qp + ec * 16);
      f32x4 y = *(const f32x4*)(qp + ec * 16 + 4);
      #pragma unroll
      for (int j = 0; j < 4; j++) { x[j] *= qs; y[j] *= qs; }
      qf[ec] = cvt8v(x, y);
    }
  }

  f32x16 acc0, acc1;
  #pragma unroll
  for (int m = 0; m < 16; m++) { acc0[m] = 0.f; acc1[m] = 0.f; }
  float zloc = 0.f;   // lane-local UNMASKED denominator partial

  const unsigned char* gsrc  = WS + (size_t)bh * NSBLK * TILE_BYTES + tid * 16;
  const unsigned char* gmask = WS + MASK_OFF + (size_t)lt * NSBLK * MTILE_BYTES + tid * 16;

  PF2(0, kb0, mb0)
  __syncthreads();

  #pragma unroll 1
  for (int tp = 0; tp < NSBLK / 2; ++tp) {
    TILE_STEP(kb0, mb0, kb1, mb1, 2 * tp)
    TILE_STEP(kb1, mb1, kb0, mb0, 2 * tp + 1)
  }

  // ---- epilogue: combine lane^32 denominator halves once ----
  {
    float zrun = zloc + __shfl_xor(zloc, 32);
    float inv = 1.0f / zrun;
    float* op = Og + ((size_t)bh * LQ + qr0 + q32) * 64 + hi * 4;
    #pragma unroll
    for (int mq = 0; mq < 4; mq++) {
      f32x4 o0, o1;
      #pragma unroll
      for (int r = 0; r < 4; r++) { o0[r] = acc0[4 * mq + r] * inv; o1[r] = acc1[4 * mq + r] * inv; }
      *(f32x4*)(op + mq * 8) = o0;
      *(f32x4*)(op + 32 + mq * 8) = o1;
    }
  }
}

// ============================================================================
// fallback (R4 kernel, with online max) for small ws
// ============================================================================
__global__ __launch_bounds__(256, 2)
void xattn_fwd(const float* __restrict__ Qg, const float* __restrict__ Kg,
               const float* __restrict__ Vg, const float* __restrict__ Mg,
               float* __restrict__ Og)
{
  __shared__ __align__(16) unsigned short Kt[64 * KSTR];
  __shared__ __align__(16) unsigned short Vt[64 * KSTR];
  const int f   = blockIdx.x + blockIdx.y * gridDim.x;
  const int xcd = f & 7;
  const int ii  = f >> 3;
  const int bh  = (xcd << 3) + (ii >> 4);
  const int lt  = ii & 15;
  const int b = bh >> 4, h = bh & 15;
  const int tid  = threadIdx.x;
  const int w    = tid >> 6;
  const int lane = tid & 63;
  const int q32  = lane & 31;
  const int hi   = lane >> 5;
  const int qr0  = lt * QTILE + w * 32;
  const float qs = 0.125f * 1.44269504088896340736f;
  bf16x8 qf[4];
  {
    const float* qp = Qg + ((size_t)b * LQ + qr0 + q32) * 1024 + h * 64 + hi * 8;
    #pragma unroll
    for (int ec = 0; ec < 4; ec++) {
      f32x4 x = *(const f32x4*)(qp + ec * 16);
      f32x4 y = *(const f32x4*)(qp + ec * 16 + 4);
      #pragma unroll
      for (int j = 0; j < 4; j++) { x[j] *= qs; y[j] *= qs; }
      qf[ec] = cvt8v(x, y);
    }
  }
  f32x16 acc0, acc1;
  #pragma unroll
  for (int m = 0; m < 16; m++) { acc0[m] = 0.f; acc1[m] = 0.f; }
  float mrun = -1e30f, zrun = 0.f;
  const int kr = tid >> 2;
  const int kc = (tid & 3) << 4;
  const int vd = tid & 63;
  const int vk0 = w << 4;
  const float* kbase = Kg + (size_t)b * SK * 1024 + h * 64;
  const float* vbase = Vg + (size_t)b * SK * 1024 + h * 64;
  const float* mbase = Mg + (size_t)(qr0 + q32) * SK + hi * 4;
  f32x4 ka, kb, kc4, kd;
  float vr[16];
  {
    const float* kp = kbase + (size_t)kr * 1024 + kc;
    ka = *(const f32x4*)kp;        kb = *(const f32x4*)(kp + 4);
    kc4 = *(const f32x4*)(kp + 8); kd = *(const f32x4*)(kp + 12);
    const float* vp = vbase + (size_t)vk0 * 1024 + vd;
    #pragma unroll
    for (int j = 0; j < 16; j++) vr[j] = vp[(size_t)j * 1024];
  }
  for (int s0 = 0; s0 < SK; s0 += 64) {
    bf16x8 kcv0 = cvt8v(ka, kb), kcv1 = cvt8v(kc4, kd);
    bf16x8 vcv0, vcv1;
    #pragma unroll
    for (int j = 0; j < 8; j++) { vcv0[j] = (bf16_t)vr[j]; vcv1[j] = (bf16_t)vr[8 + j]; }
    __syncthreads();
    *(bf16x8*)&Kt[kr * KSTR + kc] = kcv0;
    *(bf16x8*)&Kt[kr * KSTR + kc + 8] = kcv1;
    *(bf16x8*)&Vt[vd * KSTR + vk0] = vcv0;
    *(bf16x8*)&Vt[vd * KSTR + vk0 + 8] = vcv1;
    __syncthreads();
    f32x4 mk[8];
    {
      const float* mp = mbase + s0;
      #pragma unroll
      for (int kvt = 0; kvt < 2; kvt++)
        #pragma unroll
        for (int mq = 0; mq < 4; mq++)
          mk[kvt * 4 + mq] = *(const f32x4*)(mp + kvt * 32 + mq * 8);
    }
    if (s0 + 64 < SK) {
      const float* kp = kbase + (size_t)(s0 + 64 + kr) * 1024 + kc;
      ka = *(const f32x4*)kp;        kb = *(const f32x4*)(kp + 4);
      kc4 = *(const f32x4*)(kp + 8); kd = *(const f32x4*)(kp + 12);
      const float* vp = vbase + (size_t)(s0 + 64 + vk0) * 1024 + vd;
      #pragma unroll
      for (int j = 0; j < 16; j++) vr[j] = vp[(size_t)j * 1024];
    }
    f32x16 sT[2];
    #pragma unroll
    for (int m = 0; m < 16; m++) { sT[0][m] = 0.f; sT[1][m] = 0.f; }
    #pragma unroll
    for (int ec = 0; ec < 4; ec++) {
      bf16x8 kf0 = *(const bf16x8*)&Kt[q32 * KSTR + ec * 16 + hi * 8];
      sT[0] = __builtin_amdgcn_mfma_f32_32x32x16_bf16(kf0, qf[ec], sT[0], 0, 0, 0);
      bf16x8 kf1 = *(const bf16x8*)&Kt[(32 + q32) * KSTR + ec * 16 + hi * 8];
      sT[1] = __builtin_amdgcn_mfma_f32_32x32x16_bf16(kf1, qf[ec], sT[1], 0, 0, 0);
    }
    float rmax = sT[0][0];
    #pragma unroll
    for (int m = 1; m < 16; m++) rmax = fmaxf(rmax, sT[0][m]);
    #pragma unroll
    for (int m = 0; m < 16; m++) rmax = fmaxf(rmax, sT[1][m]);
    rmax = fmaxf(rmax, __shfl_xor(rmax, 32));
    if (!__all(rmax <= mrun + 6.0f)) {
      float nm = fmaxf(mrun, rmax);
      float corr = exp2f(mrun - nm);
      mrun = nm; zrun *= corr;
      #pragma unroll
      for (int m = 0; m < 16; m++) { acc0[m] *= corr; acc1[m] *= corr; }
    }
    float rs = 0.f;
    #pragma unroll
    for (int kvt = 0; kvt < 2; kvt++)
      #pragma unroll
      for (int m = 0; m < 16; m++) { sT[kvt][m] = exp2f(sT[kvt][m] - mrun); rs += sT[kvt][m]; }
    rs += __shfl_xor(rs, 32);
    zrun += rs;
    #pragma unroll
    for (int kvt = 0; kvt < 2; kvt++)
      #pragma unroll
      for (int m = 0; m < 16; m++) sT[kvt][m] *= mk[kvt * 4 + (m >> 2)][m & 3];
    bf16x8 pf[4];
    #pragma unroll
    for (int kvt = 0; kvt < 2; kvt++) {
      #pragma unroll
      for (int c = 0; c < 2; c++) {
        unsigned a0 = pk2(sT[kvt][8 * c + 0], sT[kvt][8 * c + 1]);
        unsigned a1 = pk2(sT[kvt][8 * c + 2], sT[kvt][8 * c + 3]);
        unsigned b0 = pk2(sT[kvt][8 * c + 4], sT[kvt][8 * c + 5]);
        unsigned b1 = pk2(sT[kvt][8 * c + 6], sT[kvt][8 * c + 7]);
        uint2v r02 = __builtin_amdgcn_permlane32_swap(a0, b0, false, false);
        uint2v r13 = __builtin_amdgcn_permlane32_swap(a1, b1, false, false);
        U4B8 u; u.u = uint4v{r02[0], r13[0], r02[1], r13[1]};
        pf[kvt * 2 + c] = u.v;
      }
    }
    #pragma unroll
    for (int c = 0; c < 4; c++) {
      bf16x8 vf0 = *(const bf16x8*)&Vt[q32 * KSTR + c * 16 + hi * 8];
      acc0 = __builtin_amdgcn_mfma_f32_32x32x16_bf16(vf0, pf[c], acc0, 0, 0, 0);
      bf16x8 vf1 = *(const bf16x8*)&Vt[(32 + q32) * KSTR + c * 16 + hi * 8];
      acc1 = __builtin_amdgcn_mfma_f32_32x32x16_bf16(vf1, pf[c], acc1, 0, 0, 0);
    }
  }
  {
    float inv = 1.0f / zrun;
    float* op = Og + ((size_t)bh * LQ + qr0 + q32) * 64 + hi * 4;
    #pragma unroll
    for (int mq = 0; mq < 4; mq++) {
      f32x4 o0, o1;
      #pragma unroll
      for (int r = 0; r < 4; r++) { o0[r] = acc0[4 * mq + r] * inv; o1[r] = acc1[4 * mq + r] * inv; }
      *(f32x4*)(op + mq * 8) = o0;
      *(f32x4*)(op + 32 + mq * 8) = o1;
    }
  }
}

extern "C" void kernel_launch(void* const* d_in, const int* in_sizes, int n_in,
                              void* d_out, int out_size, void* d_ws, size_t ws_size,
                              hipStream_t stream) {
  const float* Qg = (const float*)d_in[0];
  const float* Kg = (const float*)d_in[1];
  const float* Vg = (const float*)d_in[2];
  const float* Mg = (const float*)d_in[3];
  float* Og = (float*)d_out;
  if (ws_size >= WS_NEED) {
    unsigned char* ws = (unsigned char*)d_ws;
    repack_kv<<<dim3(NSBLK, 4 * NH), 256, 0, stream>>>(Kg, Vg, ws);
    repack_mask<<<dim3(NSBLK, 16), 256, 0, stream>>>(Mg, ws + MASK_OFF);
    xattn2<<<LQ / QTILE * 4 * NH, 256, 0, stream>>>(Qg, ws, Og);
  } else {
    xattn_fwd<<<dim3(LQ / QTILE, 4 * NH), 256, 0, stream>>>(Qg, Kg, Vg, Mg, Og);
  }
}